// Round 9
// baseline (45.208 us; speedup 1.0000x reference)
//
#include <hip/hip_runtime.h>

#define TSTEPS 256
#define NOBJ   8192
#define BATCH  64
#define DEMB   32
#define DATT   128

// ws layout (bytes)
#define HW_OFF     0
#define EX_OFF     32768
#define SEGOFF_OFF 196608
#define EMB_OFF    199168
#define WS_NEED    (EMB_OFF + 5 * NOBJ * DEMB * 4)

struct SP {
    const float* x[5]; const int* cls[5]; const int* seg[5];
    const float* W[5]; const float* bias[5];
    const float* x_ped; const float* x_ego; const float* h_ped;
    const float* Wp; const float* bp; const float* We; const float* be;
    const float* Wax; const float* Wah; const float* ba; const float* va;
    const float* W1; const float* b1; const float* W2; const float* b2;
    const float* W3; const float* b3;
    const int* t_ptr;
    float* out;
    float* hW;      // [64][128]
    float* ex;      // [5][8192]
    int* seg_off;   // [5][65]
    float* emb;     // [5][8192][32]
    int d[5];
    int use_emb;
};

__device__ __forceinline__ int load_t(const void* p) {
    unsigned w0 = *(const unsigned*)p;
    if (w0 < (unsigned)TSTEPS) return (int)w0;
    float f = __uint_as_float(w0);
    if (f >= 0.f && f < 256.f) return (int)f;
    return 8;
}

__device__ __forceinline__ float fast_tanh(float x) {
    float e = __expf(2.0f * x);
    return 1.0f - 2.0f / (e + 1.0f);
}

// ---- kernel 0: hW + ped/ego feats (blocks 0..63); seg_off scatter (blocks 64..223)
__global__ __launch_bounds__(256) void k_prep(SP p) {
    if (blockIdx.x >= BATCH) {
        const int g    = (blockIdx.x - BATCH) * 256 + threadIdx.x;   // 160*256 = 40960
        const int type = g >> 13;
        const int i    = g & (NOBJ - 1);
        const int* __restrict__ seg = p.seg[type];
        const int sv = seg[i];
        const int pv = (i == 0) ? -1 : seg[i - 1];
        for (int v = pv + 1; v <= sv; ++v) p.seg_off[type * 65 + v] = i;
        if (i == NOBJ - 1)
            for (int v = sv + 1; v <= BATCH; ++v) p.seg_off[type * 65 + v] = NOBJ;
        return;
    }
    const int b = blockIdx.x;
    const int j = threadIdx.x;
    const int t = load_t(p.t_ptr);
    if (j < DATT) {
        float a = p.ba[j];
        const float* h = p.h_ped + b * DEMB;
        #pragma unroll
        for (int k = 0; k < DEMB; ++k) a += h[k] * p.Wah[k * DATT + j];
        p.hW[b * DATT + j] = a;
    }
    if (j < DEMB) {
        const float* xp = p.x_ped + (size_t)(b * TSTEPS + t) * 4;
        float e = p.bp[j];
        #pragma unroll
        for (int k = 0; k < 4; ++k) e += xp[k] * p.Wp[k * DEMB + j];
        p.out[64 + b * 224 + j] = fmaxf(e, 0.f);
        const float* xe = p.x_ego + (size_t)(b * TSTEPS + t) * 4;
        float g = p.be[j];
        #pragma unroll
        for (int k = 0; k < 4; ++k) g += xe[k] * p.We[k * DEMB + j];
        p.out[64 + b * 224 + 192 + j] = fmaxf(g, 0.f);
    }
}

// ---- kernel 1: 64 objects/block, cooperative emb (no redundancy), 4 obj/thread score.
// Lane roles: s = tid>>4 (slot 0..15), q = tid&15 (j-slice of 8). Objects s+16*po.
#define EPAD 36
template<int D>
__device__ __forceinline__ void score_body(const SP& p, const int type, const int t,
                                           float* WaxT, float* embS) {
    const int tid = threadIdx.x;
    const float* __restrict__ x   = p.x[type];
    const int*   __restrict__ cls = p.cls[type];
    const int*   __restrict__ seg = p.seg[type];
    const int blkbase = blockIdx.x * 64;

    const int s = tid >> 4;
    const int q = tid & 15;

    // issue per-object metadata gathers early (latency hides under staging)
    int bseg[4], cv[4];
    #pragma unroll
    for (int po = 0; po < 4; ++po) {
        const int i = blkbase + s + 16 * po;
        bseg[po] = seg[i];
        cv[po]   = cls[i * TSTEPS + t];
    }

    // stage Wax^T (linear LDS writes, transposed global gather: L2-hot)
    for (int idx = tid; idx < DATT * DEMB; idx += 256) {
        const int j = idx >> 5, k = idx & 31;
        WaxT[idx] = p.Wax[k * DATT + j];
    }
    // compute embS[o][col] cooperatively: one element per (o,col), no redundancy.
    // Also write to ws for k_finish (coalesced: addr = base + idx).
    const float* __restrict__ Wt = p.W[type];
    const float* __restrict__ bt = p.bias[type];
    float* __restrict__ embg = p.emb + ((size_t)type * NOBJ + blkbase) * DEMB;
    for (int idx = tid; idx < 64 * DEMB; idx += 256) {
        const int o = idx >> 5, col = idx & 31;
        const float* xr = x + (size_t)((blkbase + o) * TSTEPS + t) * D;
        float a = bt[col];
        #pragma unroll
        for (int k = 0; k < D; ++k) a += xr[k] * Wt[k * DEMB + col];
        a = fmaxf(a, 0.f);
        embS[o * EPAD + col] = a;          // 2-way max (free)
        if (p.use_emb) embg[idx] = a;      // perfectly coalesced
    }
    __syncthreads();

    // main: pure LDS + FMA. acc[po][jo], j = q*8+jo.
    float acc[4][8];
    #pragma unroll
    for (int po = 0; po < 4; ++po)
        #pragma unroll
        for (int jo = 0; jo < 8; ++jo) acc[po][jo] = 0.f;

    #pragma unroll
    for (int cc = 0; cc < 8; ++cc) {
        const int ch = (cc + q) & 7;                       // WaxT rotation: 2-way (free)
        const float4 e0 = *(const float4*)&embS[(s     ) * EPAD + 4 * ch];
        const float4 e1 = *(const float4*)&embS[(s + 16) * EPAD + 4 * ch];
        const float4 e2 = *(const float4*)&embS[(s + 32) * EPAD + 4 * ch];
        const float4 e3 = *(const float4*)&embS[(s + 48) * EPAD + 4 * ch];
        #pragma unroll
        for (int jo = 0; jo < 8; ++jo) {
            const float4 w = *(const float4*)&WaxT[(q * 8 + jo) * DEMB + 4 * ch];
            acc[0][jo] += e0.x*w.x + e0.y*w.y + e0.z*w.z + e0.w*w.w;
            acc[1][jo] += e1.x*w.x + e1.y*w.y + e1.z*w.z + e1.w*w.w;
            acc[2][jo] += e2.x*w.x + e2.y*w.y + e2.z*w.z + e2.w*w.w;
            acc[3][jo] += e3.x*w.x + e3.y*w.y + e3.z*w.z + e3.w*w.w;
        }
    }

    // epilogue: hW/va gathers (L2-hot), tanh, per-object reduce over q
    float vv[8];
    *(float4*)(vv)     = *(const float4*)(p.va + q * 8);
    *(float4*)(vv + 4) = *(const float4*)(p.va + q * 8 + 4);
    float sc[4];
    #pragma unroll
    for (int po = 0; po < 4; ++po) {
        float hv[8];
        const float* hp = p.hW + bseg[po] * DATT + q * 8;
        *(float4*)(hv)     = *(const float4*)(hp);
        *(float4*)(hv + 4) = *(const float4*)(hp + 4);
        float v = 0.f;
        #pragma unroll
        for (int jo = 0; jo < 8; ++jo)
            v += fast_tanh(hv[jo] + acc[po][jo]) * vv[jo];
        sc[po] = v;
    }
    #pragma unroll
    for (int po = 0; po < 4; ++po) {
        sc[po] += __shfl_xor(sc[po], 1);
        sc[po] += __shfl_xor(sc[po], 2);
        sc[po] += __shfl_xor(sc[po], 4);
        sc[po] += __shfl_xor(sc[po], 8);
    }
    if (q == 0) {
        #pragma unroll
        for (int po = 0; po < 4; ++po)
            p.ex[type * NOBJ + blkbase + s + 16 * po] = (cv[po] != -1) ? __expf(sc[po]) : 0.f;
    }
}

__global__ __launch_bounds__(256) void k_score(SP p) {
    __shared__ __align__(16) float WaxT[DATT * DEMB];    // 16 KB
    __shared__ __align__(16) float embS[64 * EPAD];      // 9 KB
    const int t = load_t(p.t_ptr);
    switch (blockIdx.y) {
        case 0: score_body<4>(p, 0, t, WaxT, embS); break;
        case 1: score_body<6>(p, 1, t, WaxT, embS); break;
        case 2: score_body<5>(p, 2, t, WaxT, embS); break;
        case 3: score_body<7>(p, 3, t, WaxT, embS); break;
        default: score_body<7>(p, 4, t, WaxT, embS); break;
    }
}

// ---- kernel 2: per (type,segment) block: denom + probs + feature sum
__global__ __launch_bounds__(256) void k_finish(SP p) {
    const int type = blockIdx.y;
    const int bseg = blockIdx.x;
    const int tid  = threadIdx.x;
    const int j    = tid & 31;
    const int sl   = tid >> 5;   // 0..7 object slot
    const int wv   = tid >> 6;
    const float* __restrict__ ex = p.ex + type * NOBJ;
    const int lo = p.seg_off[type * 65 + bseg];
    const int hi = p.seg_off[type * 65 + bseg + 1];

    __shared__ float red4[4];
    __shared__ float ared[4][DEMB];

    float s = 0.f;
    for (int i = lo + tid; i < hi; i += 256) s += ex[i];
    #pragma unroll
    for (int off = 32; off; off >>= 1) s += __shfl_xor(s, off);
    if ((tid & 63) == 0) red4[wv] = s;
    __syncthreads();
    const float inv = 1.0f / fmaxf(red4[0] + red4[1] + red4[2] + red4[3], 1e-30f);

    float acc = 0.f;
    float* pout = p.out + 64 + BATCH * 224 + type * NOBJ;
    if (p.use_emb) {
        const float* __restrict__ eb = p.emb + (size_t)type * NOBJ * DEMB;
        for (int i = lo + sl; i < hi; i += 8) {
            const float pr = ex[i] * inv;
            if (j == 0) pout[i] = pr;
            acc += pr * eb[(size_t)i * DEMB + j];   // 128B coalesced per slot
        }
    } else {
        const int t = load_t(p.t_ptr);
        const int d = p.d[type];
        float wj[7];
        for (int k = 0; k < d; ++k) wj[k] = p.W[type][k * DEMB + j];
        const float bj = p.bias[type][j];
        for (int i = lo + sl; i < hi; i += 8) {
            const float e = ex[i];
            const float pr = e * inv;
            if (j == 0) pout[i] = pr;
            if (e > 0.f) {
                const float* xr = p.x[type] + (size_t)(i * TSTEPS + t) * d;
                float a = bj;
                for (int k = 0; k < d; ++k) a += xr[k] * wj[k];
                acc += pr * fmaxf(a, 0.f);
            }
        }
    }
    acc += __shfl_xor(acc, 32);
    if ((tid & 63) < 32) ared[wv][j] = acc;
    __syncthreads();
    if (tid < DEMB) {
        const float f = ared[0][tid] + ared[1][tid] + ared[2][tid] + ared[3][tid];
        p.out[64 + bseg * 224 + 32 * (1 + type) + tid] = f;
    }
}

// ---- kernel 3: classifier head, one wave per batch row
__global__ __launch_bounds__(64) void k_head(SP p) {
    const int b   = blockIdx.x;
    const int tid = threadIdx.x;
    const int j    = tid & 31;
    const int half = tid >> 5;
    __shared__ float h1s[DEMB];
    __shared__ float h2s[DEMB];
    const float* feats = p.out + 64 + b * 224;

    float a = 0.f;
    const int k0 = half * 112;
    #pragma unroll 4
    for (int k = k0; k < k0 + 112; ++k)
        a += feats[k] * p.W1[k * DEMB + j];
    a += __shfl_xor(a, 32);
    if (half == 0) h1s[j] = fmaxf(a + p.b1[j], 0.f);
    __syncthreads();

    float a2 = 0.f;
    const int k2 = half * 16;
    #pragma unroll
    for (int k = k2; k < k2 + 16; ++k)
        a2 += h1s[k] * p.W2[k * DEMB + j];
    a2 += __shfl_xor(a2, 32);
    if (half == 0) h2s[j] = fmaxf(a2 + p.b2[j], 0.f);
    __syncthreads();

    if (half == 0) {
        float v = h2s[j] * p.W3[j];
        v += __shfl_xor(v, 16); v += __shfl_xor(v, 8);
        v += __shfl_xor(v, 4);  v += __shfl_xor(v, 2); v += __shfl_xor(v, 1);
        if (j == 0) p.out[b] = v + p.b3[0];
    }
}

extern "C" void kernel_launch(void* const* d_in, const int* in_sizes, int n_in,
                              void* d_out, int out_size, void* d_ws, size_t ws_size,
                              hipStream_t stream) {
    (void)in_sizes; (void)n_in; (void)out_size;

    SP p;
    const int xi[5] = {3, 6, 9, 12, 15};
    const int wi[5] = {20, 22, 24, 26, 28};
    const int di[5] = {4, 6, 5, 7, 7};
    for (int tp = 0; tp < 5; ++tp) {
        p.x[tp]    = (const float*)d_in[xi[tp]];
        p.cls[tp]  = (const int*)d_in[xi[tp] + 1];
        p.seg[tp]  = (const int*)d_in[xi[tp] + 2];
        p.W[tp]    = (const float*)d_in[wi[tp]];
        p.bias[tp] = (const float*)d_in[wi[tp] + 1];
        p.d[tp]    = di[tp];
    }
    p.x_ped = (const float*)d_in[0];
    p.x_ego = (const float*)d_in[1];
    p.h_ped = (const float*)d_in[2];
    p.Wp = (const float*)d_in[18]; p.bp = (const float*)d_in[19];
    p.We = (const float*)d_in[30]; p.be = (const float*)d_in[31];
    p.Wax = (const float*)d_in[32]; p.Wah = (const float*)d_in[33];
    p.ba  = (const float*)d_in[34]; p.va  = (const float*)d_in[35];
    p.W1 = (const float*)d_in[36]; p.b1 = (const float*)d_in[37];
    p.W2 = (const float*)d_in[38]; p.b2 = (const float*)d_in[39];
    p.W3 = (const float*)d_in[40]; p.b3 = (const float*)d_in[41];
    p.t_ptr = (const int*)d_in[42];
    p.out = (float*)d_out;
    char* ws = (char*)d_ws;
    p.hW      = (float*)(ws + HW_OFF);
    p.ex      = (float*)(ws + EX_OFF);
    p.seg_off = (int*)(ws + SEGOFF_OFF);
    p.emb     = (float*)(ws + EMB_OFF);
    p.use_emb = (ws_size >= (size_t)WS_NEED) ? 1 : 0;

    hipLaunchKernelGGL(k_prep,   dim3(BATCH + 160),  dim3(256), 0, stream, p);
    hipLaunchKernelGGL(k_score,  dim3(NOBJ / 64, 5), dim3(256), 0, stream, p);
    hipLaunchKernelGGL(k_finish, dim3(BATCH, 5),     dim3(256), 0, stream, p);
    hipLaunchKernelGGL(k_head,   dim3(BATCH),        dim3(64),  0, stream, p);
}